// Round 2
// baseline (380.759 us; speedup 1.0000x reference)
//
#include <hip/hip_runtime.h>

#define SPATIAL 32768   // 32^3
#define NBINS   131072  // B(=4) * 32^3
#define FDIM    64

// ---------- order-preserving float<->uint encoding ----------
__device__ __forceinline__ unsigned int enc_f32(float f) {
    unsigned int u = __float_as_uint(f);
    return (u & 0x80000000u) ? ~u : (u | 0x80000000u);
}
__device__ __forceinline__ float dec_f32(unsigned int u) {
    u = (u & 0x80000000u) ? (u ^ 0x80000000u) : ~u;
    return __uint_as_float(u);
}

// ws word layout:
//   [0, NBINS)            counts
//   [NBINS, 2*NBINS)      cursor
//   [2*NBINS, 3*NBINS)    offsets
//   [3*NBINS, +ntot)      bin-per-point
//   [.., +ntot)           order (point indices sorted by bin)
//   last 2 words          encoded min / max

__global__ void init_ws_kernel(unsigned int* mm) {
    mm[0] = 0xFFFFFFFFu;  // encoded min accumulator
    mm[1] = 0u;           // encoded max accumulator
}

__global__ void minmax_kernel(const float4* __restrict__ pts4, int n4,
                              unsigned int* __restrict__ mm) {
    float lmin = INFINITY, lmax = -INFINITY;
    for (int i = blockIdx.x * blockDim.x + threadIdx.x; i < n4;
         i += gridDim.x * blockDim.x) {
        float4 v = pts4[i];
        lmin = fminf(fminf(lmin, v.x), fminf(v.y, v.z)); lmin = fminf(lmin, v.w);
        lmax = fmaxf(fmaxf(lmax, v.x), fmaxf(v.y, v.z)); lmax = fmaxf(lmax, v.w);
    }
    __shared__ float smin[256], smax[256];
    smin[threadIdx.x] = lmin;
    smax[threadIdx.x] = lmax;
    __syncthreads();
    for (int s = 128; s > 0; s >>= 1) {
        if (threadIdx.x < (unsigned)s) {
            smin[threadIdx.x] = fminf(smin[threadIdx.x], smin[threadIdx.x + s]);
            smax[threadIdx.x] = fmaxf(smax[threadIdx.x], smax[threadIdx.x + s]);
        }
        __syncthreads();
    }
    if (threadIdx.x == 0) {
        atomicMin(&mm[0], enc_f32(smin[0]));
        atomicMax(&mm[1], enc_f32(smax[0]));
    }
}

// Per point: compute combined bin = b*32768 + spatial, histogram it.
__global__ void bincount_kernel(const float* __restrict__ pts,
                                const unsigned int* __restrict__ mm,
                                unsigned int* __restrict__ counts,
                                unsigned int* __restrict__ binof,
                                int ntot, int N) {
    int p = blockIdx.x * blockDim.x + threadIdx.x;
    if (p >= ntot) return;
    float pmin = dec_f32(mm[0]);
    float pmax = dec_f32(mm[1]);
    float denom = pmax - pmin + 1e-6f;

    float x = pts[p * 3 + 0];
    float y = pts[p * 3 + 1];
    float z = pts[p * 3 + 2];
    // exact op order of reference: normed = (v-pmin)/denom; floor(normed*32)
    int vx = (int)floorf(((x - pmin) / denom) * 32.0f);
    int vy = (int)floorf(((y - pmin) / denom) * 32.0f);
    int vz = (int)floorf(((z - pmin) / denom) * 32.0f);
    vx = min(max(vx, 0), 31);
    vy = min(max(vy, 0), 31);
    vz = min(max(vz, 0), 31);
    int b = p / N;
    unsigned int bin = (unsigned)b * SPATIAL + vx * 1024 + vy * 32 + vz;
    binof[p] = bin;
    atomicAdd(&counts[bin], 1u);
}

// Scan stage 1: per-block (256 bins) sums.
__global__ void scan_blocksums_kernel(const unsigned int* __restrict__ counts,
                                      unsigned int* __restrict__ bsum) {
    __shared__ unsigned int s[256];
    int i = blockIdx.x * 256 + threadIdx.x;
    s[threadIdx.x] = counts[i];
    __syncthreads();
    for (int st = 128; st > 0; st >>= 1) {
        if (threadIdx.x < (unsigned)st) s[threadIdx.x] += s[threadIdx.x + st];
        __syncthreads();
    }
    if (threadIdx.x == 0) bsum[blockIdx.x] = s[0];
}

// Scan stage 2: exclusive scan of 512 block sums in one block.
__global__ void scan_top_kernel(unsigned int* __restrict__ bsum,
                                unsigned int* __restrict__ boff) {
    __shared__ unsigned int s[512];
    unsigned int v = bsum[threadIdx.x];
    s[threadIdx.x] = v;
    __syncthreads();
    for (int st = 1; st < 512; st <<= 1) {
        unsigned int add = (threadIdx.x >= (unsigned)st) ? s[threadIdx.x - st] : 0u;
        __syncthreads();
        s[threadIdx.x] += add;
        __syncthreads();
    }
    boff[threadIdx.x] = s[threadIdx.x] - v;  // exclusive
}

// Scan stage 3: per-block exclusive scan + block offset -> offsets & cursor.
__global__ void scan_write_kernel(const unsigned int* __restrict__ counts,
                                  const unsigned int* __restrict__ boff,
                                  unsigned int* __restrict__ offsets,
                                  unsigned int* __restrict__ cursor) {
    __shared__ unsigned int s[256];
    int i = blockIdx.x * 256 + threadIdx.x;
    unsigned int v = counts[i];
    s[threadIdx.x] = v;
    __syncthreads();
    for (int st = 1; st < 256; st <<= 1) {
        unsigned int add = (threadIdx.x >= (unsigned)st) ? s[threadIdx.x - st] : 0u;
        __syncthreads();
        s[threadIdx.x] += add;
        __syncthreads();
    }
    unsigned int off = boff[blockIdx.x] + s[threadIdx.x] - v;  // exclusive
    offsets[i] = off;
    cursor[i] = off;
}

// Build the per-bin ordered point-index list.
__global__ void build_order_kernel(const unsigned int* __restrict__ binof,
                                   unsigned int* __restrict__ cursor,
                                   unsigned int* __restrict__ order,
                                   int ntot) {
    int p = blockIdx.x * blockDim.x + threadIdx.x;
    if (p >= ntot) return;
    unsigned int bin = binof[p];
    unsigned int pos = atomicAdd(&cursor[bin], 1u);
    order[pos] = (unsigned)p;
}

// One 64-lane wave per bin; lane = feature channel. Writes ALL bins
// (empty -> 0), so no output memset is needed.
__global__ void gather_kernel(const float* __restrict__ feat,
                              const unsigned int* __restrict__ counts,
                              const unsigned int* __restrict__ offsets,
                              const unsigned int* __restrict__ order,
                              float* __restrict__ out) {
    int gtid = blockIdx.x * blockDim.x + threadIdx.x;
    int bin = gtid >> 6;
    int lane = threadIdx.x & 63;
    if (bin >= NBINS) return;

    unsigned int cnt = counts[bin];
    unsigned int off = offsets[bin];

    float m0 = 0.0f, m1 = 0.0f;  // zero-init grid == implicit max with 0
    unsigned int i = 0;
    for (; i + 1 < cnt; i += 2) {
        unsigned int p0 = order[off + i];
        unsigned int p1 = order[off + i + 1];
        float f0 = feat[(size_t)p0 * FDIM + lane];
        float f1 = feat[(size_t)p1 * FDIM + lane];
        m0 = fmaxf(m0, f0);
        m1 = fmaxf(m1, f1);
    }
    if (i < cnt) {
        unsigned int p0 = order[off + i];
        m0 = fmaxf(m0, feat[(size_t)p0 * FDIM + lane]);
    }
    out[(size_t)bin * FDIM + lane] = fmaxf(m0, m1);
}

// ---------- fallback (round-1 path) if ws is too small ----------
__global__ void scatter_kernel(const float* __restrict__ pts,
                               const float* __restrict__ feat,
                               const unsigned int* __restrict__ mm,
                               unsigned int* __restrict__ out,
                               int ntot, int N) {
    int lane = threadIdx.x & 63;
    int p = blockIdx.x * 4 + (threadIdx.x >> 6);
    if (p >= ntot) return;
    float pmin = dec_f32(mm[0]);
    float pmax = dec_f32(mm[1]);
    float denom = pmax - pmin + 1e-6f;
    float x = pts[p * 3 + 0], y = pts[p * 3 + 1], z = pts[p * 3 + 2];
    int vx = (int)floorf(((x - pmin) / denom) * 32.0f);
    int vy = (int)floorf(((y - pmin) / denom) * 32.0f);
    int vz = (int)floorf(((z - pmin) / denom) * 32.0f);
    vx = min(max(vx, 0), 31);
    vy = min(max(vy, 0), 31);
    vz = min(max(vz, 0), 31);
    int gidx = vx * 1024 + vy * 32 + vz;
    int b = p / N;
    float f = feat[(size_t)p * FDIM + lane];
    if (f > 0.0f) {
        atomicMax(out + ((size_t)b * SPATIAL + gidx) * FDIM + lane,
                  __float_as_uint(f));
    }
}

extern "C" void kernel_launch(void* const* d_in, const int* in_sizes, int n_in,
                              void* d_out, int out_size, void* d_ws, size_t ws_size,
                              hipStream_t stream) {
    const float* pts = (const float*)d_in[0];
    const float* feat = (const float*)d_in[1];

    int npts3 = in_sizes[0];   // B*N*3
    int ntot = npts3 / 3;      // B*N
    int B = out_size / (SPATIAL * FDIM);
    int N = ntot / B;

    unsigned int* ws = (unsigned int*)d_ws;
    unsigned int* counts  = ws;
    unsigned int* cursor  = ws + NBINS;
    unsigned int* offsets = ws + 2 * NBINS;
    unsigned int* binof   = ws + 3 * NBINS;
    unsigned int* order   = binof + ntot;
    unsigned int* mm      = order + ntot;   // 2 words
    // also reuse a chunk for scan temporaries (512+512 words after mm)
    unsigned int* bsum    = mm + 2;
    unsigned int* boff    = bsum + 512;

    size_t need = ((size_t)3 * NBINS + 2 * (size_t)ntot + 2 + 1024) * 4;
    if (ws_size < need) {
        // fallback: round-1 atomic scatter
        unsigned int* mm2 = ws;
        hipLaunchKernelGGL(init_ws_kernel, dim3(1), dim3(1), 0, stream, mm2);
        hipLaunchKernelGGL(minmax_kernel, dim3(512), dim3(256), 0, stream,
                           (const float4*)pts, npts3 / 4, mm2);
        hipMemsetAsync(d_out, 0, (size_t)out_size * sizeof(float), stream);
        hipLaunchKernelGGL(scatter_kernel, dim3((ntot + 3) / 4), dim3(256), 0,
                           stream, pts, feat, mm2, (unsigned int*)d_out, ntot, N);
        return;
    }

    hipMemsetAsync(counts, 0, (size_t)NBINS * 4, stream);
    hipLaunchKernelGGL(init_ws_kernel, dim3(1), dim3(1), 0, stream, mm);
    hipLaunchKernelGGL(minmax_kernel, dim3(512), dim3(256), 0, stream,
                       (const float4*)pts, npts3 / 4, mm);
    int pblocks = (ntot + 255) / 256;
    hipLaunchKernelGGL(bincount_kernel, dim3(pblocks), dim3(256), 0, stream,
                       pts, mm, counts, binof, ntot, N);
    hipLaunchKernelGGL(scan_blocksums_kernel, dim3(NBINS / 256), dim3(256), 0,
                       stream, counts, bsum);
    hipLaunchKernelGGL(scan_top_kernel, dim3(1), dim3(512), 0, stream,
                       bsum, boff);
    hipLaunchKernelGGL(scan_write_kernel, dim3(NBINS / 256), dim3(256), 0,
                       stream, counts, boff, offsets, cursor);
    hipLaunchKernelGGL(build_order_kernel, dim3(pblocks), dim3(256), 0, stream,
                       binof, cursor, order, ntot);
    hipLaunchKernelGGL(gather_kernel, dim3(NBINS * 64 / 256), dim3(256), 0,
                       stream, feat, counts, offsets, order, (float*)d_out);
}

// Round 3
// 275.011 us; speedup vs baseline: 1.3845x; 1.3845x over previous
//
#include <hip/hip_runtime.h>

#define SPATIAL 32768   // 32^3
#define NBINS   131072  // B(=4) * 32^3
#define FDIM    64

// ---------- order-preserving float<->uint encoding ----------
__device__ __forceinline__ unsigned int enc_f32(float f) {
    unsigned int u = __float_as_uint(f);
    return (u & 0x80000000u) ? ~u : (u | 0x80000000u);
}
__device__ __forceinline__ float dec_f32(unsigned int u) {
    u = (u & 0x80000000u) ? (u ^ 0x80000000u) : ~u;
    return __uint_as_float(u);
}

__global__ void init_ws_kernel(unsigned int* mm) {
    mm[0] = 0xFFFFFFFFu;  // encoded min accumulator
    mm[1] = 0u;           // encoded max accumulator
}

__global__ void minmax_kernel(const float4* __restrict__ pts4, int n4,
                              unsigned int* __restrict__ mm) {
    float lmin = INFINITY, lmax = -INFINITY;
    for (int i = blockIdx.x * blockDim.x + threadIdx.x; i < n4;
         i += gridDim.x * blockDim.x) {
        float4 v = pts4[i];
        lmin = fminf(fminf(lmin, v.x), fminf(v.y, v.z)); lmin = fminf(lmin, v.w);
        lmax = fmaxf(fmaxf(lmax, v.x), fmaxf(v.y, v.z)); lmax = fmaxf(lmax, v.w);
    }
    __shared__ float smin[256], smax[256];
    smin[threadIdx.x] = lmin;
    smax[threadIdx.x] = lmax;
    __syncthreads();
    for (int s = 128; s > 0; s >>= 1) {
        if (threadIdx.x < (unsigned)s) {
            smin[threadIdx.x] = fminf(smin[threadIdx.x], smin[threadIdx.x + s]);
            smax[threadIdx.x] = fmaxf(smax[threadIdx.x], smax[threadIdx.x + s]);
        }
        __syncthreads();
    }
    if (threadIdx.x == 0) {
        atomicMin(&mm[0], enc_f32(smin[0]));
        atomicMax(&mm[1], enc_f32(smax[0]));
    }
}

__global__ void bincount_kernel(const float* __restrict__ pts,
                                const unsigned int* __restrict__ mm,
                                unsigned int* __restrict__ counts,
                                unsigned int* __restrict__ binof,
                                int ntot, int N) {
    int p = blockIdx.x * blockDim.x + threadIdx.x;
    if (p >= ntot) return;
    float pmin = dec_f32(mm[0]);
    float pmax = dec_f32(mm[1]);
    float denom = pmax - pmin + 1e-6f;

    float x = pts[p * 3 + 0];
    float y = pts[p * 3 + 1];
    float z = pts[p * 3 + 2];
    int vx = (int)floorf(((x - pmin) / denom) * 32.0f);
    int vy = (int)floorf(((y - pmin) / denom) * 32.0f);
    int vz = (int)floorf(((z - pmin) / denom) * 32.0f);
    vx = min(max(vx, 0), 31);
    vy = min(max(vy, 0), 31);
    vz = min(max(vz, 0), 31);
    int b = p / N;
    unsigned int bin = (unsigned)b * SPATIAL + vx * 1024 + vy * 32 + vz;
    binof[p] = bin;
    atomicAdd(&counts[bin], 1u);
}

__global__ void scan_blocksums_kernel(const unsigned int* __restrict__ counts,
                                      unsigned int* __restrict__ bsum) {
    __shared__ unsigned int s[256];
    int i = blockIdx.x * 256 + threadIdx.x;
    s[threadIdx.x] = counts[i];
    __syncthreads();
    for (int st = 128; st > 0; st >>= 1) {
        if (threadIdx.x < (unsigned)st) s[threadIdx.x] += s[threadIdx.x + st];
        __syncthreads();
    }
    if (threadIdx.x == 0) bsum[blockIdx.x] = s[0];
}

__global__ void scan_top_kernel(unsigned int* __restrict__ bsum,
                                unsigned int* __restrict__ boff) {
    __shared__ unsigned int s[512];
    unsigned int v = bsum[threadIdx.x];
    s[threadIdx.x] = v;
    __syncthreads();
    for (int st = 1; st < 512; st <<= 1) {
        unsigned int add = (threadIdx.x >= (unsigned)st) ? s[threadIdx.x - st] : 0u;
        __syncthreads();
        s[threadIdx.x] += add;
        __syncthreads();
    }
    boff[threadIdx.x] = s[threadIdx.x] - v;  // exclusive
}

__global__ void scan_write_kernel(const unsigned int* __restrict__ counts,
                                  const unsigned int* __restrict__ boff,
                                  unsigned int* __restrict__ offsets,
                                  unsigned int* __restrict__ cursor) {
    __shared__ unsigned int s[256];
    int i = blockIdx.x * 256 + threadIdx.x;
    unsigned int v = counts[i];
    s[threadIdx.x] = v;
    __syncthreads();
    for (int st = 1; st < 256; st <<= 1) {
        unsigned int add = (threadIdx.x >= (unsigned)st) ? s[threadIdx.x - st] : 0u;
        __syncthreads();
        s[threadIdx.x] += add;
        __syncthreads();
    }
    unsigned int off = boff[blockIdx.x] + s[threadIdx.x] - v;  // exclusive
    offsets[i] = off;
    cursor[i] = off;
}

__global__ void build_order_kernel(const unsigned int* __restrict__ binof,
                                   unsigned int* __restrict__ cursor,
                                   unsigned int* __restrict__ order,
                                   int ntot) {
    int p = blockIdx.x * blockDim.x + threadIdx.x;
    if (p >= ntot) return;
    unsigned int bin = binof[p];
    unsigned int pos = atomicAdd(&cursor[bin], 1u);
    order[pos] = (unsigned)p;
}

// One 64-lane wave per bin; lane = feature channel.
// MLP-maximized gather: coalesced 64-wide index load + shfl broadcast,
// 16 independent feature loads in flight.
__global__ void gather_kernel(const float* __restrict__ feat,
                              const unsigned int* __restrict__ counts,
                              const unsigned int* __restrict__ offsets,
                              const unsigned int* __restrict__ order,
                              float* __restrict__ out) {
    int gtid = blockIdx.x * blockDim.x + threadIdx.x;
    int bin = gtid >> 6;
    int lane = threadIdx.x & 63;
    if (bin >= NBINS) return;

    unsigned int cnt = counts[bin];
    unsigned int off = offsets[bin];

    float m = 0.0f;  // zero-init grid == implicit max with 0
    unsigned int i = 0;
    while (i < cnt) {
        unsigned int nb = min(64u, cnt - i);
        // coalesced: lane l loads index of point (i+l)
        int idx = (lane < (int)nb) ? (int)order[off + i + lane] : 0;

        unsigned int j = 0;
        for (; j + 16 <= nb; j += 16) {
            float f[16];
#pragma unroll
            for (int k = 0; k < 16; ++k) {
                int p = __shfl(idx, (int)(j + k), 64);
                f[k] = feat[(size_t)p * FDIM + lane];
            }
#pragma unroll
            for (int k = 0; k < 16; ++k) m = fmaxf(m, f[k]);
        }
        for (; j + 4 <= nb; j += 4) {
            float f[4];
#pragma unroll
            for (int k = 0; k < 4; ++k) {
                int p = __shfl(idx, (int)(j + k), 64);
                f[k] = feat[(size_t)p * FDIM + lane];
            }
#pragma unroll
            for (int k = 0; k < 4; ++k) m = fmaxf(m, f[k]);
        }
        for (; j < nb; ++j) {
            int p = __shfl(idx, (int)j, 64);
            m = fmaxf(m, feat[(size_t)p * FDIM + lane]);
        }
        i += nb;
    }
    out[(size_t)bin * FDIM + lane] = m;
}

// ---------- fallback (round-1 path) if ws is too small ----------
__global__ void scatter_kernel(const float* __restrict__ pts,
                               const float* __restrict__ feat,
                               const unsigned int* __restrict__ mm,
                               unsigned int* __restrict__ out,
                               int ntot, int N) {
    int lane = threadIdx.x & 63;
    int p = blockIdx.x * 4 + (threadIdx.x >> 6);
    if (p >= ntot) return;
    float pmin = dec_f32(mm[0]);
    float pmax = dec_f32(mm[1]);
    float denom = pmax - pmin + 1e-6f;
    float x = pts[p * 3 + 0], y = pts[p * 3 + 1], z = pts[p * 3 + 2];
    int vx = (int)floorf(((x - pmin) / denom) * 32.0f);
    int vy = (int)floorf(((y - pmin) / denom) * 32.0f);
    int vz = (int)floorf(((z - pmin) / denom) * 32.0f);
    vx = min(max(vx, 0), 31);
    vy = min(max(vy, 0), 31);
    vz = min(max(vz, 0), 31);
    int gidx = vx * 1024 + vy * 32 + vz;
    int b = p / N;
    float f = feat[(size_t)p * FDIM + lane];
    if (f > 0.0f) {
        atomicMax(out + ((size_t)b * SPATIAL + gidx) * FDIM + lane,
                  __float_as_uint(f));
    }
}

extern "C" void kernel_launch(void* const* d_in, const int* in_sizes, int n_in,
                              void* d_out, int out_size, void* d_ws, size_t ws_size,
                              hipStream_t stream) {
    const float* pts = (const float*)d_in[0];
    const float* feat = (const float*)d_in[1];

    int npts3 = in_sizes[0];   // B*N*3
    int ntot = npts3 / 3;      // B*N
    int B = out_size / (SPATIAL * FDIM);
    int N = ntot / B;

    unsigned int* ws = (unsigned int*)d_ws;
    unsigned int* counts  = ws;
    unsigned int* cursor  = ws + NBINS;
    unsigned int* offsets = ws + 2 * NBINS;
    unsigned int* binof   = ws + 3 * NBINS;
    unsigned int* order   = binof + ntot;
    unsigned int* mm      = order + ntot;   // 2 words
    unsigned int* bsum    = mm + 2;
    unsigned int* boff    = bsum + 512;

    size_t need = ((size_t)3 * NBINS + 2 * (size_t)ntot + 2 + 1024) * 4;
    if (ws_size < need) {
        unsigned int* mm2 = ws;
        hipLaunchKernelGGL(init_ws_kernel, dim3(1), dim3(1), 0, stream, mm2);
        hipLaunchKernelGGL(minmax_kernel, dim3(512), dim3(256), 0, stream,
                           (const float4*)pts, npts3 / 4, mm2);
        hipMemsetAsync(d_out, 0, (size_t)out_size * sizeof(float), stream);
        hipLaunchKernelGGL(scatter_kernel, dim3((ntot + 3) / 4), dim3(256), 0,
                           stream, pts, feat, mm2, (unsigned int*)d_out, ntot, N);
        return;
    }

    hipMemsetAsync(counts, 0, (size_t)NBINS * 4, stream);
    hipLaunchKernelGGL(init_ws_kernel, dim3(1), dim3(1), 0, stream, mm);
    hipLaunchKernelGGL(minmax_kernel, dim3(512), dim3(256), 0, stream,
                       (const float4*)pts, npts3 / 4, mm);
    int pblocks = (ntot + 255) / 256;
    hipLaunchKernelGGL(bincount_kernel, dim3(pblocks), dim3(256), 0, stream,
                       pts, mm, counts, binof, ntot, N);
    hipLaunchKernelGGL(scan_blocksums_kernel, dim3(NBINS / 256), dim3(256), 0,
                       stream, counts, bsum);
    hipLaunchKernelGGL(scan_top_kernel, dim3(1), dim3(512), 0, stream,
                       bsum, boff);
    hipLaunchKernelGGL(scan_write_kernel, dim3(NBINS / 256), dim3(256), 0,
                       stream, counts, boff, offsets, cursor);
    hipLaunchKernelGGL(build_order_kernel, dim3(pblocks), dim3(256), 0, stream,
                       binof, cursor, order, ntot);
    hipLaunchKernelGGL(gather_kernel, dim3(NBINS * 64 / 256), dim3(256), 0,
                       stream, feat, counts, offsets, order, (float*)d_out);
}

// Round 4
// 273.356 us; speedup vs baseline: 1.3929x; 1.0061x over previous
//
#include <hip/hip_runtime.h>

#define SPATIAL 32768   // 32^3
#define NBINS   131072  // B(=4) * 32^3
#define FDIM    64

// ---------- order-preserving float<->uint encoding ----------
__device__ __forceinline__ unsigned int enc_f32(float f) {
    unsigned int u = __float_as_uint(f);
    return (u & 0x80000000u) ? ~u : (u | 0x80000000u);
}
__device__ __forceinline__ float dec_f32(unsigned int u) {
    u = (u & 0x80000000u) ? (u ^ 0x80000000u) : ~u;
    return __uint_as_float(u);
}

// ws word layout:
//   [0, NBINS)              counts            (memset 0)
//   [NBINS]                 nlist             (memset 0)
//   [NBINS+1]               tail              (memset 0)
//   [NBINS+2, NBINS+4)      mm: enc-min, ~enc-max  (memset 0xFF; both atomicMin)
//   [NBINS+4, 2*NBINS+4)    cursor
//   [2*NBINS+4, 3*NBINS+4)  offsets
//   [3*NBINS+4, 4*NBINS+4)  nebins (non-empty bin list)
//   [4*NBINS+4, +ntot)      binof
//   [.., +ntot)             order

// min and max both accumulate via atomicMin starting at 0xFFFFFFFF:
//   mm[0] = min(enc(v)),  mm[1] = min(~enc(v))  ->  pmax = dec(~mm[1])
__global__ void minmax_kernel(const float4* __restrict__ pts4, int n4,
                              unsigned int* __restrict__ mm) {
    float lmin = INFINITY, lmax = -INFINITY;
    for (int i = blockIdx.x * blockDim.x + threadIdx.x; i < n4;
         i += gridDim.x * blockDim.x) {
        float4 v = pts4[i];
        lmin = fminf(fminf(lmin, v.x), fminf(v.y, v.z)); lmin = fminf(lmin, v.w);
        lmax = fmaxf(fmaxf(lmax, v.x), fmaxf(v.y, v.z)); lmax = fmaxf(lmax, v.w);
    }
    __shared__ float smin[256], smax[256];
    smin[threadIdx.x] = lmin;
    smax[threadIdx.x] = lmax;
    __syncthreads();
    for (int s = 128; s > 0; s >>= 1) {
        if (threadIdx.x < (unsigned)s) {
            smin[threadIdx.x] = fminf(smin[threadIdx.x], smin[threadIdx.x + s]);
            smax[threadIdx.x] = fmaxf(smax[threadIdx.x], smax[threadIdx.x + s]);
        }
        __syncthreads();
    }
    if (threadIdx.x == 0) {
        atomicMin(&mm[0], enc_f32(smin[0]));
        atomicMin(&mm[1], ~enc_f32(smax[0]));
    }
}

__global__ void bincount_kernel(const float* __restrict__ pts,
                                const unsigned int* __restrict__ mm,
                                unsigned int* __restrict__ counts,
                                unsigned int* __restrict__ binof,
                                int ntot, int N) {
    int p = blockIdx.x * blockDim.x + threadIdx.x;
    if (p >= ntot) return;
    float pmin = dec_f32(mm[0]);
    float pmax = dec_f32(~mm[1]);
    float denom = pmax - pmin + 1e-6f;

    float x = pts[p * 3 + 0];
    float y = pts[p * 3 + 1];
    float z = pts[p * 3 + 2];
    // exact op order of reference: normed = (v-pmin)/denom; floor(normed*32)
    int vx = (int)floorf(((x - pmin) / denom) * 32.0f);
    int vy = (int)floorf(((y - pmin) / denom) * 32.0f);
    int vz = (int)floorf(((z - pmin) / denom) * 32.0f);
    vx = min(max(vx, 0), 31);
    vy = min(max(vy, 0), 31);
    vz = min(max(vz, 0), 31);
    int b = p / N;
    unsigned int bin = (unsigned)b * SPATIAL + vx * 1024 + vy * 32 + vz;
    binof[p] = bin;
    atomicAdd(&counts[bin], 1u);
}

// One thread per bin. Non-empty bins get a slot in nebins[] and a segment
// [off, off+cnt) in order[], allocated via two block-aggregated atomics.
// Replaces the 3-kernel prefix scan; order of segments is arbitrary (max is
// commutative).
__global__ void compact_kernel(const unsigned int* __restrict__ counts,
                               unsigned int* __restrict__ nlist,
                               unsigned int* __restrict__ tail,
                               unsigned int* __restrict__ nebins,
                               unsigned int* __restrict__ offsets,
                               unsigned int* __restrict__ cursor) {
    int i = blockIdx.x * 256 + threadIdx.x;
    unsigned int cnt = counts[i];
    int lane = threadIdx.x & 63;
    int wid = threadIdx.x >> 6;
    bool flag = cnt > 0;

    // wave-level: flag prefix via ballot, cnt prefix via shfl scan
    unsigned long long mask = __ballot(flag);
    unsigned int fpre = __popcll(mask & ((1ULL << lane) - 1ULL));
    unsigned int ftot = __popcll(mask);

    unsigned int cscan = cnt;
#pragma unroll
    for (int d = 1; d < 64; d <<= 1) {
        unsigned int v = __shfl_up(cscan, (unsigned)d, 64);
        if (lane >= d) cscan += v;
    }
    unsigned int cpre = cscan - cnt;                  // exclusive within wave
    unsigned int ctot = __shfl(cscan, 63, 64);        // wave total

    __shared__ unsigned int wf[4], wc[4], base[2];
    if (lane == 0) { wf[wid] = ftot; wc[wid] = ctot; }
    __syncthreads();
    unsigned int bf = 0, bc = 0;
    for (int w = 0; w < wid; ++w) { bf += wf[w]; bc += wc[w]; }
    if (threadIdx.x == 0) {
        unsigned int tf = wf[0] + wf[1] + wf[2] + wf[3];
        unsigned int tc = wc[0] + wc[1] + wc[2] + wc[3];
        base[0] = atomicAdd(nlist, tf);
        base[1] = atomicAdd(tail, tc);
    }
    __syncthreads();
    if (flag) {
        unsigned int pos = base[0] + bf + fpre;
        unsigned int off = base[1] + bc + cpre;
        nebins[pos] = (unsigned)i;
        offsets[i] = off;
        cursor[i] = off;
    }
}

__global__ void build_order_kernel(const unsigned int* __restrict__ binof,
                                   unsigned int* __restrict__ cursor,
                                   unsigned int* __restrict__ order,
                                   int ntot) {
    int p = blockIdx.x * blockDim.x + threadIdx.x;
    if (p >= ntot) return;
    unsigned int bin = binof[p];
    unsigned int pos = atomicAdd(&cursor[bin], 1u);
    order[pos] = (unsigned)p;
}

// One 64-lane wave per NON-EMPTY bin (grid-stride over device-side list).
// lane = feature channel; coalesced 64-wide index load + shfl broadcast,
// 16 independent feature loads in flight.
__global__ void gather_kernel(const float* __restrict__ feat,
                              const unsigned int* __restrict__ counts,
                              const unsigned int* __restrict__ offsets,
                              const unsigned int* __restrict__ order,
                              const unsigned int* __restrict__ nebins,
                              const unsigned int* __restrict__ nlist,
                              float* __restrict__ out) {
    int lane = threadIdx.x & 63;
    unsigned int wave = (blockIdx.x * blockDim.x + threadIdx.x) >> 6;
    unsigned int nwaves = (gridDim.x * blockDim.x) >> 6;
    unsigned int nl = *nlist;

    for (unsigned int li = wave; li < nl; li += nwaves) {
        unsigned int bin = nebins[li];
        unsigned int cnt = counts[bin];
        unsigned int off = offsets[bin];

        float m = 0.0f;  // zero-init grid == implicit max with 0
        unsigned int i = 0;
        while (i < cnt) {
            unsigned int nb = min(64u, cnt - i);
            int idx = (lane < (int)nb) ? (int)order[off + i + lane] : 0;

            unsigned int j = 0;
            for (; j + 16 <= nb; j += 16) {
                float f[16];
#pragma unroll
                for (int k = 0; k < 16; ++k) {
                    int p = __shfl(idx, (int)(j + k), 64);
                    f[k] = feat[(size_t)p * FDIM + lane];
                }
#pragma unroll
                for (int k = 0; k < 16; ++k) m = fmaxf(m, f[k]);
            }
            for (; j + 4 <= nb; j += 4) {
                float f[4];
#pragma unroll
                for (int k = 0; k < 4; ++k) {
                    int p = __shfl(idx, (int)(j + k), 64);
                    f[k] = feat[(size_t)p * FDIM + lane];
                }
#pragma unroll
                for (int k = 0; k < 4; ++k) m = fmaxf(m, f[k]);
            }
            for (; j < nb; ++j) {
                int p = __shfl(idx, (int)j, 64);
                m = fmaxf(m, feat[(size_t)p * FDIM + lane]);
            }
            i += nb;
        }
        out[(size_t)bin * FDIM + lane] = m;
    }
}

// ---------- fallback (round-1 path) if ws is too small ----------
__global__ void init_mm_kernel(unsigned int* mm) {
    mm[0] = 0xFFFFFFFFu;
    mm[1] = 0xFFFFFFFFu;
}
__global__ void scatter_kernel(const float* __restrict__ pts,
                               const float* __restrict__ feat,
                               const unsigned int* __restrict__ mm,
                               unsigned int* __restrict__ out,
                               int ntot, int N) {
    int lane = threadIdx.x & 63;
    int p = blockIdx.x * 4 + (threadIdx.x >> 6);
    if (p >= ntot) return;
    float pmin = dec_f32(mm[0]);
    float pmax = dec_f32(~mm[1]);
    float denom = pmax - pmin + 1e-6f;
    float x = pts[p * 3 + 0], y = pts[p * 3 + 1], z = pts[p * 3 + 2];
    int vx = (int)floorf(((x - pmin) / denom) * 32.0f);
    int vy = (int)floorf(((y - pmin) / denom) * 32.0f);
    int vz = (int)floorf(((z - pmin) / denom) * 32.0f);
    vx = min(max(vx, 0), 31);
    vy = min(max(vy, 0), 31);
    vz = min(max(vz, 0), 31);
    int gidx = vx * 1024 + vy * 32 + vz;
    int b = p / N;
    float f = feat[(size_t)p * FDIM + lane];
    if (f > 0.0f) {
        atomicMax(out + ((size_t)b * SPATIAL + gidx) * FDIM + lane,
                  __float_as_uint(f));
    }
}

extern "C" void kernel_launch(void* const* d_in, const int* in_sizes, int n_in,
                              void* d_out, int out_size, void* d_ws, size_t ws_size,
                              hipStream_t stream) {
    const float* pts = (const float*)d_in[0];
    const float* feat = (const float*)d_in[1];

    int npts3 = in_sizes[0];   // B*N*3
    int ntot = npts3 / 3;      // B*N
    int B = out_size / (SPATIAL * FDIM);
    int N = ntot / B;

    unsigned int* ws = (unsigned int*)d_ws;
    unsigned int* counts  = ws;
    unsigned int* nlist   = ws + NBINS;
    unsigned int* tail    = ws + NBINS + 1;
    unsigned int* mm      = ws + NBINS + 2;
    unsigned int* cursor  = ws + NBINS + 4;
    unsigned int* offsets = ws + 2 * NBINS + 4;
    unsigned int* nebins  = ws + 3 * NBINS + 4;
    unsigned int* binof   = ws + 4 * NBINS + 4;
    unsigned int* order   = binof + ntot;

    size_t need = ((size_t)4 * NBINS + 4 + 2 * (size_t)ntot) * 4;
    if (ws_size < need) {
        // fallback: round-1 atomic scatter
        unsigned int* mm2 = ws;
        hipLaunchKernelGGL(init_mm_kernel, dim3(1), dim3(1), 0, stream, mm2);
        hipLaunchKernelGGL(minmax_kernel, dim3(512), dim3(256), 0, stream,
                           (const float4*)pts, npts3 / 4, mm2);
        hipMemsetAsync(d_out, 0, (size_t)out_size * sizeof(float), stream);
        hipLaunchKernelGGL(scatter_kernel, dim3((ntot + 3) / 4), dim3(256), 0,
                           stream, pts, feat, mm2, (unsigned int*)d_out, ntot, N);
        return;
    }

    // counts + nlist + tail := 0 ; mm := 0xFFFFFFFF (both atomicMin accums)
    hipMemsetAsync(counts, 0, ((size_t)NBINS + 2) * 4, stream);
    hipMemsetAsync(mm, 0xFF, 8, stream);
    hipMemsetAsync(d_out, 0, (size_t)out_size * sizeof(float), stream);

    hipLaunchKernelGGL(minmax_kernel, dim3(512), dim3(256), 0, stream,
                       (const float4*)pts, npts3 / 4, mm);
    int pblocks = (ntot + 255) / 256;
    hipLaunchKernelGGL(bincount_kernel, dim3(pblocks), dim3(256), 0, stream,
                       pts, mm, counts, binof, ntot, N);
    hipLaunchKernelGGL(compact_kernel, dim3(NBINS / 256), dim3(256), 0, stream,
                       counts, nlist, tail, nebins, offsets, cursor);
    hipLaunchKernelGGL(build_order_kernel, dim3(pblocks), dim3(256), 0, stream,
                       binof, cursor, order, ntot);
    hipLaunchKernelGGL(gather_kernel, dim3(1024), dim3(256), 0, stream,
                       feat, counts, offsets, order, nebins, nlist,
                       (float*)d_out);
}